// Round 3
// baseline (12864.049 us; speedup 1.0000x reference)
//
#include <hip/hip_runtime.h>
#include <hip/hip_bf16.h>
#include <stdint.h>

// Problem constants (fixed by the reference): T=512, B=64, IN=H=1024, L=2
#define TT 512
#define BB 64
#define HH 1024
#define BH 65536    // B*H elements
#define KD 2048     // IN+H == H+H

typedef __attribute__((ext_vector_type(8))) short short8;
typedef __attribute__((ext_vector_type(4))) float f32x4;

__device__ __forceinline__ unsigned short f2bf(float f) {
  union { float f; unsigned int u; } v; v.f = f;
  unsigned int r = v.u + 0x7fffu + ((v.u >> 16) & 1u);  // RNE
  return (unsigned short)(r >> 16);
}
__device__ __forceinline__ float fsig(float x)  { return 1.0f / (1.0f + __expf(-x)); }
__device__ __forceinline__ float ftanhf(float x){ return 1.0f - 2.0f / (__expf(2.0f * x) + 1.0f); }

// ---------------- x -> bf16 ----------------
__global__ void cvt_x_kernel(const float* __restrict__ x, unsigned short* __restrict__ xbf) {
  const int n4 = (TT * BB * 1024) / 4;
  int stride = gridDim.x * blockDim.x;
  for (int i = blockIdx.x * blockDim.x + threadIdx.x; i < n4; i += stride) {
    float4 v = ((const float4*)x)[i];
    unsigned long long p = (unsigned long long)f2bf(v.x)
        | ((unsigned long long)f2bf(v.y) << 16)
        | ((unsigned long long)f2bf(v.z) << 32)
        | ((unsigned long long)f2bf(v.w) << 48);
    ((unsigned long long*)xbf)[i] = p;
  }
}

// ---------------- W [4096][2048] f32 -> bf16 slices [128][32][2048] ----------------
// slice g, row r: nt=r>>4, q=(r>>2)&3, jl=r&3 ; W row = q*1024 + g*8 + nt*4 + jl
__global__ void cvt_w_kernel(const float* __restrict__ W, unsigned short* __restrict__ Ws) {
  int idx = blockIdx.x * blockDim.x + threadIdx.x;   // < 128*32*512
  int k4 = idx & 511;
  int r  = (idx >> 9) & 31;
  int g  = idx >> 14;
  int grow = (((r >> 2) & 3) << 10) + (g << 3) + ((r >> 4) << 2) + (r & 3);
  float4 v = ((const float4*)(W + (size_t)grow * KD))[k4];
  unsigned long long p = (unsigned long long)f2bf(v.x)
      | ((unsigned long long)f2bf(v.y) << 16)
      | ((unsigned long long)f2bf(v.z) << 32)
      | ((unsigned long long)f2bf(v.w) << 48);
  ((unsigned long long*)(Ws + (((size_t)(g * 32 + r)) << 11)))[k4] = p;
}

// ---------------- initial h -> bf16 ----------------
__global__ void init_state_kernel(const float* __restrict__ h0in,
                                  unsigned short* h0bf, unsigned short* h1bf) {
  int i = blockIdx.x * blockDim.x + threadIdx.x;  // < BH
  h0bf[i] = f2bf(h0in[i]);
  h1bf[i] = f2bf(h0in[BH + i]);
}

// ---------------- persistent 2-layer LSTM ----------------
// 256 blocks x 512 threads. Blocks 0-127: layer0 (slice g), 128-255: layer1.
// Weights (32 gate-rows x 2048, bf16, XOR-swizzled) resident in 128KB LDS.
// c-state in registers. Step pipeline: L0@t runs concurrently with L1@t-1.
// Inter-step sync: per-block release flag + all-flags spin (agent scope).
__global__ __launch_bounds__(512) void lstm_persist(
    const unsigned short* __restrict__ W0s, const unsigned short* __restrict__ W1s,
    const float* __restrict__ b0, const float* __restrict__ b1,
    const unsigned short* __restrict__ xbf,
    unsigned short* h0bf, unsigned short* h1bf,
    const float* __restrict__ c0in, float* out, int* flags)
{
  __shared__ unsigned short wlds[32 * KD];   // 128 KB
  const int tid = threadIdx.x;
  const int bid = blockIdx.x;
  const int layer = bid >> 7;
  const int g = bid & 127;

  const unsigned short* Ws = layer ? W1s : W0s;
  const float* bias = layer ? b1 : b0;

  // ---- stage weight slice once (swizzled on the write side) ----
  {
    const unsigned short* wsrc = Ws + ((size_t)g << 16);  // g*32*2048
    int r   = tid >> 4;          // 0..31 row
    int sub = tid & 15;
    int swz = (r & 7) << 4;
#pragma unroll
    for (int it = 0; it < 16; it++) {
      int cbyte = (sub + it * 16) << 4;
      short8 v = *(const short8*)((const char*)wsrc + r * 4096 + cbyte);
      *(short8*)((char*)wlds + r * 4096 + (cbyte ^ swz)) = v;
    }
  }

  // ---- wave / lane mapping ----
  const int lane = tid & 63;
  const int w  = tid >> 6;        // 0..7
  const int mt = w & 3;           // m-tile (batch)
  const int nt = w >> 2;          // n-tile 0..1
  const int m0 = mt << 4;
  const int n  = lane & 15;
  const int hi = lane >> 4;
  const int jl = n & 3;
  const int jg = (g << 3) + (nt << 2) + jl;    // h column 0..1023
  const int nrow = (nt << 4) + n;              // LDS weight row
  const char* brow = (const char*)wlds + (nrow << 12);
  const int bswz = (nrow & 7) << 4;

  // ---- c state in registers (lanes n<4 hold 4 values each) ----
  float creg[4];
  float bi = 0.f, bfv = 0.f, bgv = 0.f, bov = 0.f;
  if (n < 4) {
    bi  = bias[jg];
    bfv = bias[1024 + jg];
    bgv = bias[2048 + jg];
    bov = bias[3072 + jg];
#pragma unroll
    for (int r = 0; r < 4; r++) {
      int m = m0 + (hi << 2) + r;
      creg[r] = c0in[(size_t)layer * BH + (m << 10) + jg];
    }
  }
  __syncthreads();

  for (int t = 0; t <= TT; t++) {
    const bool active = (layer == 0) ? (t < TT) : (t >= 1);
    if (active) {
      const int u = layer ? (t - 1) : t;
      const unsigned short *in0, *in1;
      unsigned short* hb;
      float* hf = nullptr;
      if (layer == 0) {
        in0 = xbf + (size_t)t * BH;
        in1 = h0bf + ((t & 1) << 16);
        hb  = h0bf + (((t & 1) ^ 1) << 16);
        if (t == TT - 1) hf = out + (size_t)TT * BH;     // final h, layer 0
      } else {
        in0 = h0bf + (((u & 1) ^ 1) << 16);              // h0[u]
        in1 = h1bf + ((u & 1) << 16);                    // h1[u-1]
        hb  = h1bf + (((u & 1) ^ 1) << 16);              // h1[u]
        hf  = out + (size_t)u * BH;                      // hlast[u]
      }

      const unsigned short* arow0 = in0 + ((size_t)(m0 + n) << 10) + (hi << 3);
      const unsigned short* arow1 = in1 + ((size_t)(m0 + n) << 10) + (hi << 3);

      f32x4 acc = {0.0f, 0.0f, 0.0f, 0.0f};
#pragma unroll 8
      for (int kk = 0; kk < 32; kk++) {
        short8 av = *(const short8*)(arow0 + (kk << 5));
        short8 bv = *(const short8*)(brow + (((kk << 6) + (hi << 4)) ^ bswz));
        acc = __builtin_amdgcn_mfma_f32_16x16x32_bf16(av, bv, acc, 0, 0, 0);
      }
#pragma unroll 8
      for (int kk = 0; kk < 32; kk++) {
        short8 av = *(const short8*)(arow1 + (kk << 5));
        short8 bv = *(const short8*)(brow + ((2048 + (kk << 6) + (hi << 4)) ^ bswz));
        acc = __builtin_amdgcn_mfma_f32_16x16x32_bf16(av, bv, acc, 0, 0, 0);
      }

      // ---- fused gate nonlinearity + state update ----
#pragma unroll
      for (int r = 0; r < 4; r++) {
        int src = (lane & 48) | jl;
        float vi = __shfl(acc[r], src,      64);
        float vf = __shfl(acc[r], src | 4,  64);
        float vg = __shfl(acc[r], src | 8,  64);
        float vo = __shfl(acc[r], src | 12, 64);
        if (n < 4) {
          int m = m0 + (hi << 2) + r;
          int idx = (m << 10) + jg;
          float ig = fsig(vi + bi);
          float fg = fsig(vf + bfv);
          float gg = ftanhf(vg + bgv);
          float og = fsig(vo + bov);
          float cn = ig * gg + fg * creg[r];
          float hn = og * ftanhf(cn);
          creg[r] = cn;
          hb[idx] = f2bf(hn);
          if (hf) hf[idx] = hn;
          if (layer == 1 && u == TT - 1) {
            out[(size_t)TT * BH + BH + idx] = hn;        // final h, layer 1
            out[(size_t)TT * BH + 3 * BH + idx] = cn;    // final c, layer 1
          }
          if (layer == 0 && t == TT - 1) {
            out[(size_t)TT * BH + 2 * BH + idx] = cn;    // final c, layer 0
          }
        }
      }
    }

    // ---- device-wide barrier (release own flag, spin on all 256) ----
    if (t < TT) {
      __syncthreads();   // drain this block's stores (vmcnt 0 per wave)
      if (tid == 0)
        __hip_atomic_store(&flags[bid], t + 1, __ATOMIC_RELEASE, __HIP_MEMORY_SCOPE_AGENT);
      if (tid < 256) {
        while (__hip_atomic_load(&flags[tid], __ATOMIC_RELAXED, __HIP_MEMORY_SCOPE_AGENT) < t + 1)
          __builtin_amdgcn_s_sleep(1);
      }
      if (tid == 0)
        (void)__hip_atomic_load(&flags[0], __ATOMIC_ACQUIRE, __HIP_MEMORY_SCOPE_AGENT);
      __syncthreads();
    }
  }
}

extern "C" void kernel_launch(void* const* d_in, const int* in_sizes, int n_in,
                              void* d_out, int out_size, void* d_ws, size_t ws_size,
                              hipStream_t stream) {
  (void)in_sizes; (void)n_in; (void)out_size; (void)ws_size;
  const float* x    = (const float*)d_in[0];
  const float* h0in = (const float*)d_in[1];
  const float* c0in = (const float*)d_in[2];
  const float* W0   = (const float*)d_in[3];
  const float* b0   = (const float*)d_in[4];
  const float* W1   = (const float*)d_in[5];
  const float* b1   = (const float*)d_in[6];
  float* out = (float*)d_out;

  char* ws = (char*)d_ws;
  unsigned short* Xbf  = (unsigned short*)(ws);                 // 64 MB
  unsigned short* W0s  = (unsigned short*)(ws + 67108864);      // 16 MB
  unsigned short* W1s  = (unsigned short*)(ws + 83886080);      // 16 MB
  unsigned short* h0bf = (unsigned short*)(ws + 100663296);     // 2*128KB
  unsigned short* h1bf = (unsigned short*)(ws + 100925440);     // 2*128KB
  int* flags           = (int*)(ws + 101187584);                // 1 KB

  hipMemsetAsync(flags, 0, 1024, stream);
  cvt_x_kernel<<<2048, 256, 0, stream>>>(x, Xbf);
  cvt_w_kernel<<<8192, 256, 0, stream>>>(W0, W0s);
  cvt_w_kernel<<<8192, 256, 0, stream>>>(W1, W1s);
  init_state_kernel<<<256, 256, 0, stream>>>(h0in, h0bf, h1bf);

  lstm_persist<<<256, 512, 0, stream>>>(W0s, W1s, b0, b1, Xbf,
                                        h0bf, h1bf, c0in, out, flags);
}

// Round 4
// 10104.359 us; speedup vs baseline: 1.2731x; 1.2731x over previous
//
#include <hip/hip_runtime.h>
#include <hip/hip_bf16.h>
#include <stdint.h>

// Problem constants (fixed by the reference): T=512, B=64, IN=H=1024, L=2
#define TT 512
#define BB 64
#define HH 1024
#define BH 65536    // B*H elements
#define KD 2048     // IN+H == H+H

typedef __attribute__((ext_vector_type(8))) short short8;
typedef __attribute__((ext_vector_type(4))) float f32x4;

__device__ __forceinline__ unsigned short f2bf(float f) {
  union { float f; unsigned int u; } v; v.f = f;
  unsigned int r = v.u + 0x7fffu + ((v.u >> 16) & 1u);  // RNE
  return (unsigned short)(r >> 16);
}
__device__ __forceinline__ float fsig(float x)  { return 1.0f / (1.0f + __expf(-x)); }
__device__ __forceinline__ float ftanhf(float x){ return 1.0f - 2.0f / (__expf(2.0f * x) + 1.0f); }

// ---------------- x -> bf16 ----------------
__global__ void cvt_x_kernel(const float* __restrict__ x, unsigned short* __restrict__ xbf) {
  const int n4 = (TT * BB * 1024) / 4;
  int stride = gridDim.x * blockDim.x;
  for (int i = blockIdx.x * blockDim.x + threadIdx.x; i < n4; i += stride) {
    float4 v = ((const float4*)x)[i];
    unsigned long long p = (unsigned long long)f2bf(v.x)
        | ((unsigned long long)f2bf(v.y) << 16)
        | ((unsigned long long)f2bf(v.z) << 32)
        | ((unsigned long long)f2bf(v.w) << 48);
    ((unsigned long long*)xbf)[i] = p;
  }
}

// ---------------- W [4096][2048] f32 -> bf16 slices [128][32][2048] ----------------
// slice g, row r: nt=r>>4, q=(r>>2)&3, jl=r&3 ; W row = q*1024 + g*8 + nt*4 + jl
__global__ void cvt_w_kernel(const float* __restrict__ W, unsigned short* __restrict__ Ws) {
  int idx = blockIdx.x * blockDim.x + threadIdx.x;   // < 128*32*512
  int k4 = idx & 511;
  int r  = (idx >> 9) & 31;
  int g  = idx >> 14;
  int grow = (((r >> 2) & 3) << 10) + (g << 3) + ((r >> 4) << 2) + (r & 3);
  float4 v = ((const float4*)(W + (size_t)grow * KD))[k4];
  unsigned long long p = (unsigned long long)f2bf(v.x)
      | ((unsigned long long)f2bf(v.y) << 16)
      | ((unsigned long long)f2bf(v.z) << 32)
      | ((unsigned long long)f2bf(v.w) << 48);
  ((unsigned long long*)(Ws + (((size_t)(g * 32 + r)) << 11)))[k4] = p;
}

// ---------------- initial h -> hist slot 0 ----------------
__global__ void init_state_kernel(const float* __restrict__ h0in,
                                  unsigned short* h0s0, unsigned short* h1s0) {
  int i = blockIdx.x * blockDim.x + threadIdx.x;  // < BH
  h0s0[i] = f2bf(h0in[i]);
  h1s0[i] = f2bf(h0in[BH + i]);
}

// ---------------- persistent 2-layer LSTM ----------------
// 256 blocks x 512 threads, 1 block/CU (128KB LDS pigeonhole). Blocks 0-127:
// layer0, 128-255: layer1 (pipelined one step behind). Weights resident in LDS.
// c-state in registers. h communicated through WRITE-ONCE history slots:
// h?hist[s] = h after s steps. Stores are relaxed agent-scope atomics (sc1,
// write-through to LLC); loads are plain cached loads (safe: line never cached
// before first write within a dispatch; kernel-start L2 invalidate covers
// graph replays). Sync: per-block monotone flag + spin; NO acquire/release
// fences (no buffer_inv / buffer_wbl2).
__global__ __launch_bounds__(512) void lstm_persist(
    const unsigned short* __restrict__ W0s, const unsigned short* __restrict__ W1s,
    const float* __restrict__ b0, const float* __restrict__ b1,
    const unsigned short* __restrict__ xbf,
    unsigned short* h0hist, unsigned short* h1hist,
    const float* __restrict__ c0in, float* out, int* flags)
{
  __shared__ unsigned short wlds[32 * KD];   // 128 KB
  const int tid = threadIdx.x;
  const int bid = blockIdx.x;
  const int layer = bid >> 7;
  const int g = bid & 127;

  const unsigned short* Ws = layer ? W1s : W0s;
  const float* bias = layer ? b1 : b0;

  // ---- stage weight slice once (swizzled on the write side) ----
  {
    const unsigned short* wsrc = Ws + ((size_t)g << 16);  // g*32*2048
    int r   = tid >> 4;          // 0..31 row
    int sub = tid & 15;
    int swz = (r & 7) << 4;
#pragma unroll
    for (int it = 0; it < 16; it++) {
      int cbyte = (sub + it * 16) << 4;
      short8 v = *(const short8*)((const char*)wsrc + r * 4096 + cbyte);
      *(short8*)((char*)wlds + r * 4096 + (cbyte ^ swz)) = v;
    }
  }

  // ---- wave / lane mapping ----
  const int lane = tid & 63;
  const int w  = tid >> 6;        // 0..7
  const int mt = w & 3;           // m-tile (batch)
  const int nt = w >> 2;          // n-tile 0..1
  const int m0 = mt << 4;
  const int n  = lane & 15;
  const int hi = lane >> 4;
  const int jl = n & 3;
  const int jg = (g << 3) + (nt << 2) + jl;    // h column 0..1023
  const int nrow = (nt << 4) + n;              // LDS weight row
  const char* brow = (const char*)wlds + (nrow << 12);
  const int bswz = (nrow & 7) << 4;

  // ---- c state in registers (lanes n<4 hold 4 values each) ----
  float creg[4];
  float bi = 0.f, bfv = 0.f, bgv = 0.f, bov = 0.f;
  if (n < 4) {
    bi  = bias[jg];
    bfv = bias[1024 + jg];
    bgv = bias[2048 + jg];
    bov = bias[3072 + jg];
#pragma unroll
    for (int r = 0; r < 4; r++) {
      int m = m0 + (hi << 2) + r;
      creg[r] = c0in[(size_t)layer * BH + (m << 10) + jg];
    }
  }
  __syncthreads();

  for (int t = 0; t <= TT; t++) {
    const bool active = (layer == 0) ? (t < TT) : (t >= 1);
    if (active) {
      const int u = layer ? (t - 1) : t;
      const unsigned short *in0, *in1;
      unsigned short* hb;
      float* hf = nullptr;
      if (layer == 0) {
        in0 = xbf + (size_t)t * BH;                      // x_t
        in1 = h0hist + (size_t)t * BH;                   // h0 after t steps
        hb  = h0hist + (size_t)(t + 1) * BH;             // h0 after t+1 steps
        if (t == TT - 1) hf = out + (size_t)TT * BH;     // final h, layer 0
      } else {
        in0 = h0hist + (size_t)(u + 1) * BH;             // h0[u] (slot u+1)
        in1 = h1hist + (size_t)u * BH;                   // h1 after u steps
        hb  = h1hist + (size_t)(u + 1) * BH;             // h1 after u+1 steps
        hf  = out + (size_t)u * BH;                      // hlast[u]
      }
      unsigned int* hb32 = (unsigned int*)hb;

      const unsigned short* arow0 = in0 + ((size_t)(m0 + n) << 10) + (hi << 3);
      const unsigned short* arow1 = in1 + ((size_t)(m0 + n) << 10) + (hi << 3);

      f32x4 acc = {0.0f, 0.0f, 0.0f, 0.0f};
#pragma unroll 8
      for (int kk = 0; kk < 32; kk++) {
        short8 av = *(const short8*)(arow0 + (kk << 5));
        short8 bv = *(const short8*)(brow + (((kk << 6) + (hi << 4)) ^ bswz));
        acc = __builtin_amdgcn_mfma_f32_16x16x32_bf16(av, bv, acc, 0, 0, 0);
      }
#pragma unroll 8
      for (int kk = 0; kk < 32; kk++) {
        short8 av = *(const short8*)(arow1 + (kk << 5));
        short8 bv = *(const short8*)(brow + ((2048 + (kk << 6) + (hi << 4)) ^ bswz));
        acc = __builtin_amdgcn_mfma_f32_16x16x32_bf16(av, bv, acc, 0, 0, 0);
      }

      // ---- fused gate nonlinearity + state update ----
      const int src = (lane & 48) | jl;
#pragma unroll
      for (int r = 0; r < 4; r++) {
        float vi = __shfl(acc[r], src,      64);
        float vf = __shfl(acc[r], src | 4,  64);
        float vg = __shfl(acc[r], src | 8,  64);
        float vo = __shfl(acc[r], src | 12, 64);
        float hn = 0.f;
        int m = m0 + (hi << 2) + r;
        int idx = (m << 10) + jg;
        if (n < 4) {
          float ig = fsig(vi + bi);
          float fg = fsig(vf + bfv);
          float gg = ftanhf(vg + bgv);
          float og = fsig(vo + bov);
          float cn = ig * gg + fg * creg[r];
          hn = og * ftanhf(cn);
          creg[r] = cn;
          if (hf) hf[idx] = hn;
          if (layer == 1 && u == TT - 1) {
            out[(size_t)TT * BH + BH + idx] = hn;        // final h, layer 1
            out[(size_t)TT * BH + 3 * BH + idx] = cn;    // final c, layer 1
          }
          if (layer == 0 && t == TT - 1) {
            out[(size_t)TT * BH + 2 * BH + idx] = cn;    // final c, layer 0
          }
        }
        // pack 2 adjacent columns into u32, write-through (sc1) atomic store
        float hn2 = __shfl(hn, lane + 1, 64);
        if (n < 4 && (n & 1) == 0) {
          unsigned int pack = (unsigned int)f2bf(hn) | ((unsigned int)f2bf(hn2) << 16);
          __hip_atomic_store(hb32 + (idx >> 1), pack, __ATOMIC_RELAXED, __HIP_MEMORY_SCOPE_AGENT);
        }
      }
    }

    // ---- fence-free device barrier ----
    if (t < TT) {
      __syncthreads();   // compiler emits vmcnt(0) drain: h stores acked at LLC
      if (tid == 0)
        __hip_atomic_store(&flags[bid], t + 1, __ATOMIC_RELAXED, __HIP_MEMORY_SCOPE_AGENT);
      const int lim = (layer == 0) ? 128 : 256;   // L0 never consumes L1 data
      if (tid < lim) {
        while (__hip_atomic_load(&flags[tid], __ATOMIC_RELAXED, __HIP_MEMORY_SCOPE_AGENT) < t + 1)
          __builtin_amdgcn_s_sleep(1);
      }
      asm volatile("" ::: "memory");
      __syncthreads();
    }
  }
}

extern "C" void kernel_launch(void* const* d_in, const int* in_sizes, int n_in,
                              void* d_out, int out_size, void* d_ws, size_t ws_size,
                              hipStream_t stream) {
  (void)in_sizes; (void)n_in; (void)out_size; (void)ws_size;
  const float* x    = (const float*)d_in[0];
  const float* h0in = (const float*)d_in[1];
  const float* c0in = (const float*)d_in[2];
  const float* W0   = (const float*)d_in[3];
  const float* b0   = (const float*)d_in[4];
  const float* W1   = (const float*)d_in[5];
  const float* b1   = (const float*)d_in[6];
  float* out = (float*)d_out;

  char* ws = (char*)d_ws;
  const size_t HIST = (size_t)(TT + 1) * BH * sizeof(unsigned short);  // 67,239,936 B
  unsigned short* Xbf    = (unsigned short*)(ws);                      // 64 MB
  unsigned short* W0s    = (unsigned short*)(ws + 67108864);           // 16 MB
  unsigned short* W1s    = (unsigned short*)(ws + 83886080);           // 16 MB
  unsigned short* h0hist = (unsigned short*)(ws + 100663296);          // 64.1 MB
  unsigned short* h1hist = (unsigned short*)(ws + 100663296 + HIST);   // 64.1 MB
  int* flags             = (int*)(ws + 100663296 + 2 * HIST);          // 1 KB

  hipMemsetAsync(flags, 0, 1024, stream);
  cvt_x_kernel<<<2048, 256, 0, stream>>>(x, Xbf);
  cvt_w_kernel<<<8192, 256, 0, stream>>>(W0, W0s);
  cvt_w_kernel<<<8192, 256, 0, stream>>>(W1, W1s);
  init_state_kernel<<<256, 256, 0, stream>>>(h0in, h0hist, h1hist);

  lstm_persist<<<256, 512, 0, stream>>>(W0s, W1s, b0, b1, Xbf,
                                        h0hist, h1hist, c0in, out, flags);
}